// Round 9
// baseline (475.581 us; speedup 1.0000x reference)
//
#include <hip/hip_runtime.h>
#include <hip/hip_bf16.h>

#define N_PTS 65536
#define K_CB  8192
#define D_DIM 64
#define CAPH  31   // candidate slots per row PER CODE-HALF (private region, count at +31)

typedef float f32x4 __attribute__((ext_vector_type(4)));
typedef short s16x8 __attribute__((ext_vector_type(8)));

typedef __attribute__((address_space(1))) const unsigned int gu32;
typedef __attribute__((address_space(3))) unsigned int lu32;

__device__ __forceinline__ unsigned bfpack2(float a, float b) {
    union { __hip_bfloat162 h2; unsigned u; } cv;
    cv.h2 = __float22bfloat162_rn(make_float2(a, b));   // RNE pair cvt (v_cvt_pk_bf16_f32)
    return cv.u;
}

// async global->LDS, 16B/lane; LDS dest = wave-uniform base + laneID*16
__device__ __forceinline__ void gl2lds16(const void* g, void* lds) {
    __builtin_amdgcn_global_load_lds((gu32*)g, (lu32*)lds, 16, 0, 0);
}

// DPP max within 16-lane rows (reduction domain = tx group, DPP-row aligned)
template <int CTRL>
__device__ __forceinline__ float dpp_fmax(float v) {
    int s = __builtin_amdgcn_update_dpp(0, __float_as_int(v), CTRL, 0xf, 0xf, true);
    return fmaxf(v, __int_as_float(s));
}

// Candidate region layout (R9): rescore-block b = row>>8 owns out-words
// [b*16384, (b+1)*16384). Plane h at +h*8192; row j=row&255 at +j*32
// (slots 0..30, count at +31). Coarse block (tile,half) thus owns a contiguous
// EXCLUSIVE 16 KB ([ +h*8192 + (tile&1)*4096, +4096 words )) -- no two blocks
// write within 16 KB of each other at any time (kills R7/R8's cross-XCD
// ownership ping-pong, which was granularity >= 256B per the R8 null result).
__device__ __forceinline__ size_t cand_base(int row, int h) {
    return (size_t)(row >> 8) * 16384 + (size_t)h * 8192 + (size_t)(row & 255) * 32;
}

// ---- node 0: codebook fp32 -> bf16 pre-swizzled in LDS-image order; zero counters ----
__global__ __launch_bounds__(256) void vq_pack(
        const float* __restrict__ cb, unsigned short* __restrict__ cbswz,
        int* __restrict__ cand) {
    int g = blockIdx.x * 256 + threadIdx.x;
    int row = g >> 3, s = g & 7;
    int u = (s ^ (row & 7)) * 8;
    const float4* p = (const float4*)(cb + (size_t)row * D_DIM + u);
    float4 a = p[0], b = p[1];
    uint4 pk;
    pk.x = bfpack2(a.x, a.y); pk.y = bfpack2(a.z, a.w);
    pk.z = bfpack2(b.x, b.y); pk.w = bfpack2(b.z, b.w);
    *(uint4*)(cbswz + (size_t)row * 64 + s * 8) = pk;
    cand[cand_base(g, 0) + 31] = 0;       // count, code-half 0 (g spans all z-rows)
    cand[cand_base(g, 1) + 31] = 0;       // count, code-half 1
}

// ---- node 1: e2[K], e2n[K] = -e2/2, x2[N] (numpy-pairwise exact) + per-block e2 maxes ----
__global__ __launch_bounds__(256) void vq_prep(
        const float* __restrict__ z, const float* __restrict__ cb,
        float* __restrict__ e2, float* __restrict__ e2n,
        float* __restrict__ x2, float* __restrict__ bmax) {
#pragma clang fp contract(off)
    __shared__ float sm[4];
    int b = blockIdx.x;
    int lane = threadIdx.x & 63;
    int wv = threadIdx.x >> 6;
    const float* src; float* dst; int row0; bool iscb;
    if (b < 128) { src = cb; dst = e2; row0 = b * 64 + wv * 16; iscb = true; }
    else         { src = z;  dst = x2; row0 = (b - 128) * 64 + wv * 16; iscb = false; }
    float lmax = 0.f;
    for (int r = 0; r < 16; ++r) {
        int row = row0 + r;
        float v = src[(size_t)row * D_DIM + lane];
        float w = v * v;
        float ra = w;
#pragma unroll
        for (int i = 1; i < 8; ++i) ra = ra + __shfl(w, lane + 8 * i, 64);
        float r0 = __shfl(ra, 0, 64), r1 = __shfl(ra, 1, 64),
              r2 = __shfl(ra, 2, 64), r3 = __shfl(ra, 3, 64),
              r4 = __shfl(ra, 4, 64), r5 = __shfl(ra, 5, 64),
              r6 = __shfl(ra, 6, 64), r7 = __shfl(ra, 7, 64);
        if (lane == 0) {
            float s = ((r0 + r1) + (r2 + r3)) + ((r4 + r5) + (r6 + r7));
            dst[row] = s;
            if (iscb) e2n[row] = -0.5f * s;   // pre-scaled MFMA bias
            lmax = fmaxf(lmax, s);
        }
    }
    if (b < 128) {                 // block-uniform branch: syncthreads is safe
        if (lane == 0) sm[wv] = lmax;
        __syncthreads();
        if (threadIdx.x == 0)
            bmax[b] = fmaxf(fmaxf(sm[0], sm[1]), fmaxf(sm[2], sm[3]));
    }
}

// stage one 128-row codebook chunk (16 KB, pre-swizzled) + its e2n slice, async.
__device__ __forceinline__ void stage_chunk(
        const unsigned short* __restrict__ cbS, const float* __restrict__ e2S,
        unsigned short* bufb, float* e2hb, int kc, int w, int l) {
    const char* gbase = (const char*)(cbS + (size_t)kc * 128 * 64);
#pragma unroll
    for (int j = 0; j < 2; ++j) {
        int off = j * 8192 + w * 1024;               // wave-uniform LDS base
        gl2lds16(gbase + off + l * 16, (char*)bufb + off);
    }
    if (w == 0 && l < 32)                             // 128 floats, lanes 0..31
        gl2lds16(e2S + kc * 128 + l * 4, e2hb);
}

// ---- node 2: coarse argmin with online candidate collection ----
// bias -e2/2 in MFMA C-init => t = -2*acc; min-t == max-acc.
// Collect acc >= prefixMax - W/2 (superset guarantee).
// v10 = v9 geometry (1024 blocks: tile = bid>>1, code half = bid&1; 4 blocks/CU
// = 8 waves/SIMD; LDS counters, no device atomics) + the 16KB-exclusive
// candidate region layout (see cand_base). Soundness unchanged: half-prefix max
// <= full-prefix max -> looser-but-sound windows; chunks 0,1 exempt (Amin=3e38
// until the it=1 update over 256 codes), revisited at it=32,33. Rescore's exact
// lexicographic argmin over the superset -> outputs identical.
__global__ __launch_bounds__(512, 8) void vq_coarse(
        const float* __restrict__ z, const unsigned short* __restrict__ cbswz,
        const float* __restrict__ e2n, const float* __restrict__ x2,
        const float* __restrict__ bmax, int* __restrict__ cand) {
    __shared__ __align__(16) unsigned short pool[2][128 * 64];   // 32 KB
    __shared__ __align__(16) float e2h[2][128];                  // 1 KB
    __shared__ int cntS[128];
    const int tid = threadIdx.x;
    const int w = tid >> 6, l = tid & 63, tx = l & 15, q = l >> 4;
    const int n0 = (blockIdx.x >> 1) * 128;          // z-tile
    const int hsel = blockIdx.x & 1;                 // code half
    const int koff = hsel * (K_CB / 2);
    const size_t cb0 = cand_base(n0, hsel);          // this block's 16KB region base
    const unsigned short* cbS = cbswz + (size_t)koff * 64;
    const float* e2S = e2n + koff;

    if (tid < 128) cntS[tid] = 0;

    // stage z tile fp32->bf16, swizzled (one-time; proven conflict-free layout)
#pragma unroll
    for (int i = 0; i < 2; ++i) {
        int lin = tid + 512 * i;
        int row = lin >> 3, u = lin & 7;
        const float4* p = (const float4*)(z + (size_t)(n0 + row) * D_DIM + u * 8);
        float4 a = p[0], b2 = p[1];
        uint4 pk;
        pk.x = bfpack2(a.x, a.y);   pk.y = bfpack2(a.z, a.w);
        pk.z = bfpack2(b2.x, b2.y); pk.w = bfpack2(b2.z, b2.w);
        *(uint4*)&pool[0][row * 64 + ((u ^ (row & 7)) * 8)] = pk;
    }

    float e2m;   // global e2max from prep's per-block maxes
    {
        float v = fmaxf(bmax[l], bmax[l + 64]);
#pragma unroll
        for (int m = 1; m < 64; m <<= 1) v = fmaxf(v, __shfl_xor(v, m, 64));
        e2m = v;
    }

    float halfW[4], A[4], M[4];
#pragma unroll
    for (int i = 0; i < 4; ++i) {
        int row = n0 + w * 16 + q * 4 + i;
        halfW[i] = 0.0175f * sqrtf(x2[row] * e2m) + 1e-4f;   // W/2, proven constant
        A[i] = 3.0e38f;      // no collection during chunks 0,1 (revisited at end)
        M[i] = -3.4e38f;
    }
    float Amin = 3.0e38f;

    __syncthreads();                       // z tile visible to all waves
    s16x8 afr[2];                          // A-frags register-resident for whole kernel
#pragma unroll
    for (int ks = 0; ks < 2; ++ks) {
        int row = w * 16 + tx;
        afr[ks] = *(const s16x8*)&pool[0][row * 64 + (((ks * 4 + q) ^ (tx & 7)) * 8)];
    }
    __syncthreads();                       // all waves done with z tile -> pool reusable

    stage_chunk(cbS, e2S, pool[0], e2h[0], 0, w, l);
    __syncthreads();                       // implicit vmcnt(0): chunk 0 resident

    for (int it = 0; it < 34; ++it) {      // 32 chunks + revisit of chunks 0,1
        const int kc = (it < 32) ? it : it - 32;
        const int cur = it & 1;
        if (it < 33) {                     // issue next-chunk stage BEFORE compute
            int nk = (it + 1 < 32) ? it + 1 : it - 31;
            stage_chunk(cbS, e2S, pool[cur ^ 1], e2h[cur ^ 1], nk, w, l);
        }

        const unsigned short* cbb = pool[cur];
        const float* e2c = e2h[cur];
#pragma unroll
        for (int ct = 0; ct < 8; ++ct) {
            int crow = ct * 16 + tx;
            float bias = e2c[crow];        // already -e2/2 (prep pre-scale)
            s16x8 b0 = *(const s16x8*)&cbb[crow * 64 + ((q ^ (tx & 7)) * 8)];
            s16x8 b1 = *(const s16x8*)&cbb[crow * 64 + (((4 + q) ^ (tx & 7)) * 8)];
            f32x4 acc = {bias, bias, bias, bias};
            acc = __builtin_amdgcn_mfma_f32_16x16x32_bf16(afr[0], b0, acc, 0, 0, 0);
            acc = __builtin_amdgcn_mfma_f32_16x16x32_bf16(afr[1], b1, acc, 0, 0, 0);
            M[0] = fmaxf(M[0], acc[0]);
            M[1] = fmaxf(M[1], acc[1]);
            M[2] = fmaxf(M[2], acc[2]);
            M[3] = fmaxf(M[3], acc[3]);
            // entry filter: superset of any(acc[r] >= A[r]); exact per-element
            // predicates re-checked inside -> identical candidate set.
            float amax = fmaxf(fmaxf(acc[0], acc[1]), fmaxf(acc[2], acc[3]));
            if (amax >= Amin) {            // rare; false during it=0,1 (Amin=3e38)
                int kglob = koff + kc * 128 + crow;
#pragma unroll
                for (int r = 0; r < 4; ++r) {
                    if (acc[r] >= A[r]) {
                        int lrow = w * 16 + q * 4 + r;
                        int slot = atomicAdd(&cntS[lrow], 1);   // LDS: cheap
                        if (slot < CAPH)
                            cand[cb0 + (size_t)lrow * 32 + slot] = kglob;
                    }
                }
            }
        }
        // first update at end of it=1 (256-code prefix); then every chunk.
        if (it >= 1 && it < 32) {
#pragma unroll
            for (int i = 0; i < 4; ++i) {
                float v = M[i];
                v = dpp_fmax<0xB1>(v);    // quad_perm [1,0,3,2]  (xor 1)
                v = dpp_fmax<0x4E>(v);    // quad_perm [2,3,0,1]  (xor 2)
                v = dpp_fmax<0x124>(v);   // row_ror:4  (combine quads)
                v = dpp_fmax<0x128>(v);   // row_ror:8  (full 16-lane max)
                M[i] = v;
                A[i] = v - halfW[i];
            }
            Amin = fminf(fminf(A[0], A[1]), fminf(A[2], A[3]));
        }
        __syncthreads();   // drains vmcnt (stage issued ~full phase ago) + buffer handoff
    }
    if (tid < 128)         // publish this half's count (word 31 of own region)
        cand[cb0 + (size_t)tid * 32 + 31] = cntS[tid];
}

// ---- exact fp32 rescore: bit-identical to the proven pipeline ----
__device__ __forceinline__ float exact_score(const float* zr, const float* __restrict__ cb,
                                             const float* __restrict__ e2, float x2v, int k) {
    const float4* c4 = (const float4*)(cb + (size_t)k * D_DIM);
    float g = 0.f;
#pragma unroll
    for (int j = 0; j < 16; ++j) {
        float4 v = c4[j];
        g = fmaf(zr[4 * j + 0], v.x, g);
        g = fmaf(zr[4 * j + 1], v.y, g);
        g = fmaf(zr[4 * j + 2], v.z, g);
        g = fmaf(zr[4 * j + 3], v.w, g);
    }
    return fmaf(-2.f, g, x2v) + e2[k];
}

// ---- node 3: rescore + gather + straight-through write + loss partials ----
// 2 threads per row; thread-half h scans code-half h's private region
// (cand_base(n,h), count at +31), merged via shfl_xor(1) under the exact
// (score, k) lexicographic order -> identical argmin. NOTE: this rescore
// block's zq writes (out words [b*16384,(b+1)*16384)) overlap OTHER rows' slot
// regions WITHIN THE SAME BLOCK only -> a block-wide __syncthreads() between
// the last slot read and the first zq write makes the aliasing safe.
// Straight-through write, per-row lsum, and the 256-leaf reduction tree are
// unchanged -> loss bit-identical.
__global__ __launch_bounds__(512, 2) void vq_rescore(
        const float* __restrict__ z, const float* __restrict__ cb,
        const float* __restrict__ e2, const float* __restrict__ x2,
        int* __restrict__ slots, float* __restrict__ idx_out,
        float* __restrict__ partials) {
    int tid = threadIdx.x;
    int r = tid >> 1, half = tid & 1;
    int n = blockIdx.x * 256 + r;
    float zr[64];
    const float4* z4 = (const float4*)(z + (size_t)n * D_DIM);
#pragma unroll
    for (int i = 0; i < 16; ++i) {
        float4 v = z4[i];
        zr[4 * i] = v.x; zr[4 * i + 1] = v.y; zr[4 * i + 2] = v.z; zr[4 * i + 3] = v.w;
    }
    float x2v = x2[n];
    size_t base_h = cand_base(n, half);
    int c0 = slots[cand_base(n, 0) + 31];
    int c1 = slots[cand_base(n, 1) + 31];
    bool ovf = (c0 > CAPH) | (c1 > CAPH);
    int myc = half ? c1 : c0;
    if (myc > CAPH) myc = CAPH;
    float bs = 3.4e38f; int bk = 0x7fffffff;
    if (!ovf) {
        for (int i = 0; i < myc; ++i) {
            int k = slots[base_h + i];
            float s = exact_score(zr, cb, e2, x2v, k);
            if (s < bs || (s == bs && k < bk)) { bs = s; bk = k; }
        }
    }
    // wave-cooperative full scan for overflowed rows (exact; rare);
    // only the half==0 lane of a pair flags; merge propagates to the partner.
    unsigned long long mask = __ballot(ovf && half == 0);
    while (mask) {
        int src = __ffsll((long long)mask) - 1;
        mask &= (mask - 1);
        int rown = __shfl(n, src, 64);
        float x2s = __shfl(x2v, src, 64);
        float zs[64];
        const float4* zz = (const float4*)(z + (size_t)rown * D_DIM);
#pragma unroll
        for (int i = 0; i < 16; ++i) {
            float4 v = zz[i];
            zs[4 * i] = v.x; zs[4 * i + 1] = v.y; zs[4 * i + 2] = v.z; zs[4 * i + 3] = v.w;
        }
        float fb = 3.4e38f; int fk = 0x7fffffff;
        for (int k = (tid & 63); k < K_CB; k += 64) {
            float s = exact_score(zs, cb, e2, x2s, k);
            if (s < fb || (s == fb && k < fk)) { fb = s; fk = k; }
        }
#pragma unroll
        for (int m = 1; m < 64; m <<= 1) {
            float ov = __shfl_xor(fb, m, 64);
            int   ok = __shfl_xor(fk, m, 64);
            if (ov < fb || (ov == fb && ok < fk)) { fb = ov; fk = ok; }
        }
        if ((tid & 63) == src) { bs = fb; bk = fk; }
    }
    // pair merge: exact lexicographic (score, k) min over both halves
    {
        float ov = __shfl_xor(bs, 1, 64);
        int   ok = __shfl_xor(bk, 1, 64);
        if (ov < bs || (ov == bs && ok < bk)) { bs = ov; bk = ok; }
    }
    __syncthreads();   // ALL slot reads in this block complete before any zq write

    __shared__ float red[256];
    if (half == 0) {
        idx_out[n] = (float)bk;
        float lsum = 0.f;
        const float4* c4 = (const float4*)(cb + (size_t)bk * D_DIM);
        float4* o4 = (float4*)((float*)slots + (size_t)n * 64);   // zq row, float view
#pragma unroll
        for (int j = 0; j < 16; ++j) {
            float4 c = c4[j];
            float4 o;
            float d0 = c.x - zr[4 * j];     o.x = zr[4 * j]     + d0;
            float d1 = c.y - zr[4 * j + 1]; o.y = zr[4 * j + 1] + d1;
            float d2 = c.z - zr[4 * j + 2]; o.z = zr[4 * j + 2] + d2;
            float d3 = c.w - zr[4 * j + 3]; o.w = zr[4 * j + 3] + d3;
            lsum += d0 * d0 + d1 * d1 + d2 * d2 + d3 * d3;
            o4[j] = o;
        }
        red[r] = lsum;
    }
    __syncthreads();
    for (int s = 128; s > 0; s >>= 1) {
        if (tid < s) red[tid] += red[tid + s];
        __syncthreads();
    }
    if (tid == 0) partials[blockIdx.x] = red[0];
}

// ---- node 4: final loss ----
__global__ void vq_final(const float* __restrict__ partials, float* __restrict__ loss_out) {
    __shared__ float red[256];
    int tid = threadIdx.x;
    red[tid] = partials[tid];
    __syncthreads();
    for (int s = 128; s > 0; s >>= 1) {
        if (tid < s) red[tid] += red[tid + s];
        __syncthreads();
    }
    if (tid == 0) *loss_out = 1.25f * red[0] / (float)(N_PTS * D_DIM);
}

extern "C" void kernel_launch(void* const* d_in, const int* in_sizes, int n_in,
                              void* d_out, int out_size, void* d_ws, size_t ws_size,
                              hipStream_t stream) {
    const float* z  = (const float*)d_in[0];
    const float* cb = (const float*)d_in[1];
    float* out      = (float*)d_out;
    float* zq_out   = out;                          // [N*64]; doubles as cand region
    float* loss_out = out + (size_t)N_PTS * D_DIM;  // [1]
    float* idx_out  = loss_out + 1;                 // [N]; [0..127] doubles as bmax scratch

    // workspace: partials(256f) | e2(K f) | e2n(K f) | x2(N f) | cbswz(K*64 bf16, 1 MB)
    float* wsf = (float*)d_ws;
    float* partials = wsf;
    float* e2  = wsf + 256;
    float* e2n = wsf + 256 + K_CB;
    float* x2  = wsf + 256 + 2 * K_CB;
    unsigned short* cbswz = (unsigned short*)(wsf + 256 + 2 * K_CB + N_PTS);  // 16B-aligned

    int* cand = (int*)zq_out;
    float* bmax = idx_out;                          // overwritten by rescore afterwards

    vq_pack   <<<K_CB * 8 / 256, 256, 0, stream>>>(cb, cbswz, cand);
    vq_prep   <<<128 + N_PTS / 64, 256, 0, stream>>>(z, cb, e2, e2n, x2, bmax);
    vq_coarse <<<2 * (N_PTS / 128), 512, 0, stream>>>(z, cbswz, e2n, x2, bmax, cand);
    vq_rescore<<<N_PTS / 256, 512, 0, stream>>>(z, cb, e2, x2, cand, idx_out, partials);
    vq_final  <<<1, 256, 0, stream>>>(partials, loss_out);
}

// Round 10
// 314.211 us; speedup vs baseline: 1.5136x; 1.5136x over previous
//
#include <hip/hip_runtime.h>
#include <hip/hip_bf16.h>

#define N_PTS 65536
#define K_CB  8192
#define D_DIM 64
#define CAPH  31   // candidate slots per row PER CODE-HALF (region word 31 = count)

typedef float f32x4 __attribute__((ext_vector_type(4)));
typedef short s16x8 __attribute__((ext_vector_type(8)));

typedef __attribute__((address_space(1))) const unsigned int gu32;
typedef __attribute__((address_space(3))) unsigned int lu32;

__device__ __forceinline__ unsigned bfpack2(float a, float b) {
    union { __hip_bfloat162 h2; unsigned u; } cv;
    cv.h2 = __float22bfloat162_rn(make_float2(a, b));   // RNE pair cvt (v_cvt_pk_bf16_f32)
    return cv.u;
}

// async global->LDS, 16B/lane; LDS dest = wave-uniform base + laneID*16
__device__ __forceinline__ void gl2lds16(const void* g, void* lds) {
    __builtin_amdgcn_global_load_lds((gu32*)g, (lu32*)lds, 16, 0, 0);
}

// DPP max within 16-lane rows (reduction domain = tx group, DPP-row aligned)
template <int CTRL>
__device__ __forceinline__ float dpp_fmax(float v) {
    int s = __builtin_amdgcn_update_dpp(0, __float_as_int(v), CTRL, 0xf, 0xf, true);
    return fmaxf(v, __int_as_float(s));
}

// Candidate region layout (R9, kept): rescore-block b = row>>8 owns out-words
// [b*16384, (b+1)*16384). Plane h at +h*8192; row j=row&255 at +j*32
// (slots 0..30, count at +31). Coarse block (tile,half) owns an exclusive,
// contiguous 16 KB and (R10) writes it exactly ONCE, coalesced, at kernel end.
__device__ __forceinline__ size_t cand_base(int row, int h) {
    return (size_t)(row >> 8) * 16384 + (size_t)h * 8192 + (size_t)(row & 255) * 32;
}

// ---- node 0: codebook fp32 -> bf16, stored pre-swizzled in LDS-image order ----
// image[k*64 + s*8 + e] = bf16(cb[k][(s ^ (k&7))*8 + e])  -- bit-identical bytes
// to the original in-kernel cbb fill, so coarse scores are unchanged.
__global__ __launch_bounds__(256) void vq_pack(
        const float* __restrict__ cb, unsigned short* __restrict__ cbswz) {
    int g = blockIdx.x * 256 + threadIdx.x;
    int row = g >> 3, s = g & 7;
    int u = (s ^ (row & 7)) * 8;
    const float4* p = (const float4*)(cb + (size_t)row * D_DIM + u);
    float4 a = p[0], b = p[1];
    uint4 pk;
    pk.x = bfpack2(a.x, a.y); pk.y = bfpack2(a.z, a.w);
    pk.z = bfpack2(b.x, b.y); pk.w = bfpack2(b.z, b.w);
    *(uint4*)(cbswz + (size_t)row * 64 + s * 8) = pk;
}

// ---- node 1: e2[K], e2n[K] = -e2/2, x2[N] (numpy-pairwise exact) + per-block e2 maxes ----
__global__ __launch_bounds__(256) void vq_prep(
        const float* __restrict__ z, const float* __restrict__ cb,
        float* __restrict__ e2, float* __restrict__ e2n,
        float* __restrict__ x2, float* __restrict__ bmax) {
#pragma clang fp contract(off)
    __shared__ float sm[4];
    int b = blockIdx.x;
    int lane = threadIdx.x & 63;
    int wv = threadIdx.x >> 6;
    const float* src; float* dst; int row0; bool iscb;
    if (b < 128) { src = cb; dst = e2; row0 = b * 64 + wv * 16; iscb = true; }
    else         { src = z;  dst = x2; row0 = (b - 128) * 64 + wv * 16; iscb = false; }
    float lmax = 0.f;
    for (int r = 0; r < 16; ++r) {
        int row = row0 + r;
        float v = src[(size_t)row * D_DIM + lane];
        float w = v * v;
        float ra = w;
#pragma unroll
        for (int i = 1; i < 8; ++i) ra = ra + __shfl(w, lane + 8 * i, 64);
        float r0 = __shfl(ra, 0, 64), r1 = __shfl(ra, 1, 64),
              r2 = __shfl(ra, 2, 64), r3 = __shfl(ra, 3, 64),
              r4 = __shfl(ra, 4, 64), r5 = __shfl(ra, 5, 64),
              r6 = __shfl(ra, 6, 64), r7 = __shfl(ra, 7, 64);
        if (lane == 0) {
            float s = ((r0 + r1) + (r2 + r3)) + ((r4 + r5) + (r6 + r7));
            dst[row] = s;
            if (iscb) e2n[row] = -0.5f * s;   // pre-scaled MFMA bias
            lmax = fmaxf(lmax, s);
        }
    }
    if (b < 128) {                 // block-uniform branch: syncthreads is safe
        if (lane == 0) sm[wv] = lmax;
        __syncthreads();
        if (threadIdx.x == 0)
            bmax[b] = fmaxf(fmaxf(sm[0], sm[1]), fmaxf(sm[2], sm[3]));
    }
}

// stage one 128-row codebook chunk (16 KB, pre-swizzled) + its e2n slice, async.
__device__ __forceinline__ void stage_chunk(
        const unsigned short* __restrict__ cbS, const float* __restrict__ e2S,
        unsigned short* bufb, float* e2hb, int kc, int w, int l) {
    const char* gbase = (const char*)(cbS + (size_t)kc * 128 * 64);
#pragma unroll
    for (int j = 0; j < 2; ++j) {
        int off = j * 8192 + w * 1024;               // wave-uniform LDS base
        gl2lds16(gbase + off + l * 16, (char*)bufb + off);
    }
    if (w == 0 && l < 32)                             // 128 floats, lanes 0..31
        gl2lds16(e2S + kc * 128 + l * 4, e2hb);
}

// ---- node 2: coarse argmin with online candidate collection ----
// bias -e2/2 in MFMA C-init => t = -2*acc; min-t == max-acc.
// Collect acc >= prefixMax - W/2 (superset guarantee).
// v11 = v10 geometry (1024 blocks: tile = bid>>1, code half = bid&1) with
// candidates collected ENTIRELY IN LDS (ushort, k<8192) and flushed ONCE at
// kernel end as a coalesced 16 KB burst into the exclusive region. This removes
// all mid-loop scattered global stores -- the proven root cause (R7-R9) of the
// L2 thrash that killed codebook reuse (FETCH 888 MB) and re-wrote candidate
// lines ~15x (WRITE 255 MB). LDS 42.5 KB -> 3 blocks/CU = 6 waves/SIMD.
// Soundness unchanged: half-prefix max <= full-prefix max -> looser-but-sound
// windows; chunks 0,1 exempt (Amin=3e38 until the it=1 update over 256 codes),
// revisited at it=32,33 with the full half-prefix. Rescore's exact
// lexicographic argmin over the superset -> outputs identical.
__global__ __launch_bounds__(512, 6) void vq_coarse(
        const float* __restrict__ z, const unsigned short* __restrict__ cbswz,
        const float* __restrict__ e2n, const float* __restrict__ x2,
        const float* __restrict__ bmax, int* __restrict__ cand) {
    __shared__ __align__(16) unsigned short pool[2][128 * 64];   // 32 KB
    __shared__ __align__(16) float e2h[2][128];                  // 1 KB
    __shared__ int cntS[128];                                    // 0.5 KB
    __shared__ unsigned short candS[128][32];                    // 8 KB (slots 0..30 used)
    const int tid = threadIdx.x;
    const int w = tid >> 6, l = tid & 63, tx = l & 15, q = l >> 4;
    const int n0 = (blockIdx.x >> 1) * 128;          // z-tile
    const int hsel = blockIdx.x & 1;                 // code half
    const int koff = hsel * (K_CB / 2);
    const size_t cb0 = cand_base(n0, hsel);          // this block's 16KB region base
    const unsigned short* cbS = cbswz + (size_t)koff * 64;
    const float* e2S = e2n + koff;

    if (tid < 128) cntS[tid] = 0;

    // stage z tile fp32->bf16, swizzled (one-time; proven conflict-free layout)
#pragma unroll
    for (int i = 0; i < 2; ++i) {
        int lin = tid + 512 * i;
        int row = lin >> 3, u = lin & 7;
        const float4* p = (const float4*)(z + (size_t)(n0 + row) * D_DIM + u * 8);
        float4 a = p[0], b2 = p[1];
        uint4 pk;
        pk.x = bfpack2(a.x, a.y);   pk.y = bfpack2(a.z, a.w);
        pk.z = bfpack2(b2.x, b2.y); pk.w = bfpack2(b2.z, b2.w);
        *(uint4*)&pool[0][row * 64 + ((u ^ (row & 7)) * 8)] = pk;
    }

    float e2m;   // global e2max from prep's per-block maxes
    {
        float v = fmaxf(bmax[l], bmax[l + 64]);
#pragma unroll
        for (int m = 1; m < 64; m <<= 1) v = fmaxf(v, __shfl_xor(v, m, 64));
        e2m = v;
    }

    float halfW[4], A[4], M[4];
#pragma unroll
    for (int i = 0; i < 4; ++i) {
        int row = n0 + w * 16 + q * 4 + i;
        halfW[i] = 0.0175f * sqrtf(x2[row] * e2m) + 1e-4f;   // W/2, proven constant
        A[i] = 3.0e38f;      // no collection during chunks 0,1 (revisited at end)
        M[i] = -3.4e38f;
    }
    float Amin = 3.0e38f;

    __syncthreads();                       // z tile visible to all waves
    s16x8 afr[2];                          // A-frags register-resident for whole kernel
#pragma unroll
    for (int ks = 0; ks < 2; ++ks) {
        int row = w * 16 + tx;
        afr[ks] = *(const s16x8*)&pool[0][row * 64 + (((ks * 4 + q) ^ (tx & 7)) * 8)];
    }
    __syncthreads();                       // all waves done with z tile -> pool reusable

    stage_chunk(cbS, e2S, pool[0], e2h[0], 0, w, l);
    __syncthreads();                       // implicit vmcnt(0): chunk 0 resident

    for (int it = 0; it < 34; ++it) {      // 32 chunks + revisit of chunks 0,1
        const int kc = (it < 32) ? it : it - 32;
        const int cur = it & 1;
        if (it < 33) {                     // issue next-chunk stage BEFORE compute
            int nk = (it + 1 < 32) ? it + 1 : it - 31;
            stage_chunk(cbS, e2S, pool[cur ^ 1], e2h[cur ^ 1], nk, w, l);
        }

        const unsigned short* cbb = pool[cur];
        const float* e2c = e2h[cur];
#pragma unroll
        for (int ct = 0; ct < 8; ++ct) {
            int crow = ct * 16 + tx;
            float bias = e2c[crow];        // already -e2/2 (prep pre-scale)
            s16x8 b0 = *(const s16x8*)&cbb[crow * 64 + ((q ^ (tx & 7)) * 8)];
            s16x8 b1 = *(const s16x8*)&cbb[crow * 64 + (((4 + q) ^ (tx & 7)) * 8)];
            f32x4 acc = {bias, bias, bias, bias};
            acc = __builtin_amdgcn_mfma_f32_16x16x32_bf16(afr[0], b0, acc, 0, 0, 0);
            acc = __builtin_amdgcn_mfma_f32_16x16x32_bf16(afr[1], b1, acc, 0, 0, 0);
            M[0] = fmaxf(M[0], acc[0]);
            M[1] = fmaxf(M[1], acc[1]);
            M[2] = fmaxf(M[2], acc[2]);
            M[3] = fmaxf(M[3], acc[3]);
            // entry filter: superset of any(acc[r] >= A[r]); exact per-element
            // predicates re-checked inside -> identical candidate set.
            float amax = fmaxf(fmaxf(acc[0], acc[1]), fmaxf(acc[2], acc[3]));
            if (amax >= Amin) {            // rare; false during it=0,1 (Amin=3e38)
                int kglob = koff + kc * 128 + crow;
#pragma unroll
                for (int r = 0; r < 4; ++r) {
                    if (acc[r] >= A[r]) {
                        int lrow = w * 16 + q * 4 + r;
                        int slot = atomicAdd(&cntS[lrow], 1);   // LDS: cheap
                        if (slot < CAPH)
                            candS[lrow][slot] = (unsigned short)kglob;   // LDS only
                    }
                }
            }
        }
        // first update at end of it=1 (256-code prefix); then every chunk.
        if (it >= 1 && it < 32) {
#pragma unroll
            for (int i = 0; i < 4; ++i) {
                float v = M[i];
                v = dpp_fmax<0xB1>(v);    // quad_perm [1,0,3,2]  (xor 1)
                v = dpp_fmax<0x4E>(v);    // quad_perm [2,3,0,1]  (xor 2)
                v = dpp_fmax<0x124>(v);   // row_ror:4  (combine quads)
                v = dpp_fmax<0x128>(v);   // row_ror:8  (full 16-lane max)
                M[i] = v;
                A[i] = v - halfW[i];
            }
            Amin = fminf(fminf(A[0], A[1]), fminf(A[2], A[3]));
        }
        __syncthreads();   // drains vmcnt (stage issued ~full phase ago) + buffer handoff
    }

    // single coalesced flush: 128 rows x 32 ints (slots widened; count in word 31).
    // Thread t -> row t>>2, word-group (t&3)*8; consecutive threads contiguous.
    {
        int row = tid >> 2, g = (tid & 3) * 8;
        int vals[8];
#pragma unroll
        for (int i = 0; i < 8; ++i) {
            int wd = g + i;
            vals[i] = (wd == 31) ? cntS[row] : (int)candS[row][wd];
        }
        *(int4*)&cand[cb0 + (size_t)row * 32 + g]     = make_int4(vals[0], vals[1], vals[2], vals[3]);
        *(int4*)&cand[cb0 + (size_t)row * 32 + g + 4] = make_int4(vals[4], vals[5], vals[6], vals[7]);
    }
}

// ---- exact fp32 rescore: bit-identical to the proven pipeline ----
__device__ __forceinline__ float exact_score(const float* zr, const float* __restrict__ cb,
                                             const float* __restrict__ e2, float x2v, int k) {
    const float4* c4 = (const float4*)(cb + (size_t)k * D_DIM);
    float g = 0.f;
#pragma unroll
    for (int j = 0; j < 16; ++j) {
        float4 v = c4[j];
        g = fmaf(zr[4 * j + 0], v.x, g);
        g = fmaf(zr[4 * j + 1], v.y, g);
        g = fmaf(zr[4 * j + 2], v.z, g);
        g = fmaf(zr[4 * j + 3], v.w, g);
    }
    return fmaf(-2.f, g, x2v) + e2[k];
}

// ---- node 3: rescore + gather + straight-through write + loss partials ----
// 2 threads per row; thread-half h scans code-half h's private region
// (cand_base(n,h), count at +31), merged via shfl_xor(1) under the exact
// (score, k) lexicographic order -> identical argmin. Block-wide __syncthreads
// between the last slot read and the first zq write makes the intra-block
// aliasing safe. Straight-through write, per-row lsum, and the 256-leaf
// reduction tree are unchanged -> loss bit-identical.
__global__ __launch_bounds__(512, 2) void vq_rescore(
        const float* __restrict__ z, const float* __restrict__ cb,
        const float* __restrict__ e2, const float* __restrict__ x2,
        int* __restrict__ slots, float* __restrict__ idx_out,
        float* __restrict__ partials) {
    int tid = threadIdx.x;
    int r = tid >> 1, half = tid & 1;
    int n = blockIdx.x * 256 + r;
    float zr[64];
    const float4* z4 = (const float4*)(z + (size_t)n * D_DIM);
#pragma unroll
    for (int i = 0; i < 16; ++i) {
        float4 v = z4[i];
        zr[4 * i] = v.x; zr[4 * i + 1] = v.y; zr[4 * i + 2] = v.z; zr[4 * i + 3] = v.w;
    }
    float x2v = x2[n];
    size_t base_h = cand_base(n, half);
    int c0 = slots[cand_base(n, 0) + 31];
    int c1 = slots[cand_base(n, 1) + 31];
    bool ovf = (c0 > CAPH) | (c1 > CAPH);
    int myc = half ? c1 : c0;
    if (myc > CAPH) myc = CAPH;
    float bs = 3.4e38f; int bk = 0x7fffffff;
    if (!ovf) {
        for (int i = 0; i < myc; ++i) {
            int k = slots[base_h + i];
            float s = exact_score(zr, cb, e2, x2v, k);
            if (s < bs || (s == bs && k < bk)) { bs = s; bk = k; }
        }
    }
    // wave-cooperative full scan for overflowed rows (exact; rare);
    // only the half==0 lane of a pair flags; merge propagates to the partner.
    unsigned long long mask = __ballot(ovf && half == 0);
    while (mask) {
        int src = __ffsll((long long)mask) - 1;
        mask &= (mask - 1);
        int rown = __shfl(n, src, 64);
        float x2s = __shfl(x2v, src, 64);
        float zs[64];
        const float4* zz = (const float4*)(z + (size_t)rown * D_DIM);
#pragma unroll
        for (int i = 0; i < 16; ++i) {
            float4 v = zz[i];
            zs[4 * i] = v.x; zs[4 * i + 1] = v.y; zs[4 * i + 2] = v.z; zs[4 * i + 3] = v.w;
        }
        float fb = 3.4e38f; int fk = 0x7fffffff;
        for (int k = (tid & 63); k < K_CB; k += 64) {
            float s = exact_score(zs, cb, e2, x2s, k);
            if (s < fb || (s == fb && k < fk)) { fb = s; fk = k; }
        }
#pragma unroll
        for (int m = 1; m < 64; m <<= 1) {
            float ov = __shfl_xor(fb, m, 64);
            int   ok = __shfl_xor(fk, m, 64);
            if (ov < fb || (ov == fb && ok < fk)) { fb = ov; fk = ok; }
        }
        if ((tid & 63) == src) { bs = fb; bk = fk; }
    }
    // pair merge: exact lexicographic (score, k) min over both halves
    {
        float ov = __shfl_xor(bs, 1, 64);
        int   ok = __shfl_xor(bk, 1, 64);
        if (ov < bs || (ov == bs && ok < bk)) { bs = ov; bk = ok; }
    }
    __syncthreads();   // ALL slot reads in this block complete before any zq write

    __shared__ float red[256];
    if (half == 0) {
        idx_out[n] = (float)bk;
        float lsum = 0.f;
        const float4* c4 = (const float4*)(cb + (size_t)bk * D_DIM);
        float4* o4 = (float4*)((float*)slots + (size_t)n * 64);   // zq row, float view
#pragma unroll
        for (int j = 0; j < 16; ++j) {
            float4 c = c4[j];
            float4 o;
            float d0 = c.x - zr[4 * j];     o.x = zr[4 * j]     + d0;
            float d1 = c.y - zr[4 * j + 1]; o.y = zr[4 * j + 1] + d1;
            float d2 = c.z - zr[4 * j + 2]; o.z = zr[4 * j + 2] + d2;
            float d3 = c.w - zr[4 * j + 3]; o.w = zr[4 * j + 3] + d3;
            lsum += d0 * d0 + d1 * d1 + d2 * d2 + d3 * d3;
            o4[j] = o;
        }
        red[r] = lsum;
    }
    __syncthreads();
    for (int s = 128; s > 0; s >>= 1) {
        if (tid < s) red[tid] += red[tid + s];
        __syncthreads();
    }
    if (tid == 0) partials[blockIdx.x] = red[0];
}

// ---- node 4: final loss ----
__global__ void vq_final(const float* __restrict__ partials, float* __restrict__ loss_out) {
    __shared__ float red[256];
    int tid = threadIdx.x;
    red[tid] = partials[tid];
    __syncthreads();
    for (int s = 128; s > 0; s >>= 1) {
        if (tid < s) red[tid] += red[tid + s];
        __syncthreads();
    }
    if (tid == 0) *loss_out = 1.25f * red[0] / (float)(N_PTS * D_DIM);
}

extern "C" void kernel_launch(void* const* d_in, const int* in_sizes, int n_in,
                              void* d_out, int out_size, void* d_ws, size_t ws_size,
                              hipStream_t stream) {
    const float* z  = (const float*)d_in[0];
    const float* cb = (const float*)d_in[1];
    float* out      = (float*)d_out;
    float* zq_out   = out;                          // [N*64]; doubles as cand region
    float* loss_out = out + (size_t)N_PTS * D_DIM;  // [1]
    float* idx_out  = loss_out + 1;                 // [N]; [0..127] doubles as bmax scratch

    // workspace: partials(256f) | e2(K f) | e2n(K f) | x2(N f) | cbswz(K*64 bf16, 1 MB)
    float* wsf = (float*)d_ws;
    float* partials = wsf;
    float* e2  = wsf + 256;
    float* e2n = wsf + 256 + K_CB;
    float* x2  = wsf + 256 + 2 * K_CB;
    unsigned short* cbswz = (unsigned short*)(wsf + 256 + 2 * K_CB + N_PTS);  // 16B-aligned

    int* cand = (int*)zq_out;
    float* bmax = idx_out;                          // overwritten by rescore afterwards

    vq_pack   <<<K_CB * 8 / 256, 256, 0, stream>>>(cb, cbswz);
    vq_prep   <<<128 + N_PTS / 64, 256, 0, stream>>>(z, cb, e2, e2n, x2, bmax);
    vq_coarse <<<2 * (N_PTS / 128), 512, 0, stream>>>(z, cbswz, e2n, x2, bmax, cand);
    vq_rescore<<<N_PTS / 256, 512, 0, stream>>>(z, cb, e2, x2, cand, idx_out, partials);
    vq_final  <<<1, 256, 0, stream>>>(partials, loss_out);
}